// Round 14
// baseline (209.404 us; speedup 1.0000x reference)
//
#include <hip/hip_runtime.h>
#include <stdint.h>

// Problem constants
#define Bn 4
#define Tn 2048
#define En 1024
#define Hn 16
#define HSn 64
#define BHn (Bn*Hn)   // 64
#define NRn (Bn*Tn)   // 8192

// exp(x/32) = exp2(x * 0.03125 * log2(e)); folded into Wq at k_wT time.
#define CEXP 0.0450840831f

typedef __attribute__((ext_vector_type(8))) short short8;
typedef __attribute__((ext_vector_type(4))) float f32x4;
typedef __attribute__((ext_vector_type(16))) float f32x16;
typedef __attribute__((ext_vector_type(4))) unsigned int uint4w;

__device__ __forceinline__ unsigned short f2b(float f){
  union { float f; unsigned int u; } c; c.f = f;
  unsigned int u = c.u + 0x7FFFu + ((c.u >> 16) & 1u);
  return (unsigned short)(u >> 16);
}
__device__ __forceinline__ float b2f(unsigned short s){
  union { unsigned int u; float f; } c; c.u = ((unsigned int)s) << 16;
  return c.f;
}
__device__ __forceinline__ unsigned int cvtpk(float lo, float hi){
  unsigned int r;
  asm("v_cvt_pk_bf16_f32 %0, %1, %2" : "=v"(r) : "v"(lo), "v"(hi));
  return r;
}
__device__ __forceinline__ f32x4 mfma16(short8 a, short8 b, f32x4 c){
  return __builtin_amdgcn_mfma_f32_16x16x32_bf16(a, b, c, 0, 0, 0);
}
__device__ __forceinline__ f32x16 mfma32(short8 a, short8 b, f32x16 c){
  return __builtin_amdgcn_mfma_f32_32x32x16_bf16(a, b, c, 0, 0, 0);
}
__device__ __forceinline__ void gl16(const void* g, void* s){
  __builtin_amdgcn_global_load_lds((const __attribute__((address_space(1))) unsigned int*)g,
                                   (__attribute__((address_space(3))) unsigned int*)s, 16, 0, 0);
}
#define FENCE()    asm volatile("" ::: "memory")
#define WAITV(N)   asm volatile("s_waitcnt vmcnt(" #N ")" ::: "memory")
#define SBAR()     __builtin_amdgcn_s_barrier()

// ---------------- kernel 0: x fp32 -> bf16 ----------------
__global__ void k_cvt_x(const float* __restrict__ x, unsigned short* __restrict__ xb){
  int i = (blockIdx.x * blockDim.x + threadIdx.x) * 8;
  float4 a = *(const float4*)(x + i);
  float4 b = *(const float4*)(x + i + 4);
  alignas(16) unsigned short o[8] = {f2b(a.x),f2b(a.y),f2b(a.z),f2b(a.w),
                                     f2b(b.x),f2b(b.y),f2b(b.z),f2b(b.w)};
  *(uint4w*)(xb + i) = *(const uint4w*)o;
}

// ---------------- kernel 0b: weight convert+transpose (Wq pre-scaled) --------
__global__ void k_wT(const float* __restrict__ Wq, const float* __restrict__ Wk,
                     const float* __restrict__ Wv, const float* __restrict__ Wo,
                     unsigned short* __restrict__ Wt, unsigned short* __restrict__ Wot)
{
  __shared__ unsigned short Ls[64*80];
  const int tid = threadIdx.x;
  const int ey = blockIdx.x, jt = blockIdx.y;
  const int e0 = ey*64;
  const float* src; int R, c0; unsigned short* outp; float sc = 1.0f;
  if (jt < 48){
    int sel = jt >> 4, h = jt & 15;
    const float* W = (sel==0)?Wq:((sel==1)?Wk:Wv);
    if (sel == 0) sc = CEXP;          // fold exp2 conversion+1/32 into Q
    src = W + h*(En*HSn); R = HSn; c0 = 0;
    outp = Wt + jt*64*En;
  } else {
    src = Wo; R = En; c0 = (jt-48)*64;
    outp = Wot + (jt-48)*64*En;
  }
  {
    const int e = tid >> 2, cq = (tid & 3)*16;
    const float* p = src + (e0 + e)*R + c0 + cq;
    float vv[16];
    *(float4*)&vv[0]  = *(const float4*)(p);
    *(float4*)&vv[4]  = *(const float4*)(p+4);
    *(float4*)&vv[8]  = *(const float4*)(p+8);
    *(float4*)&vv[12] = *(const float4*)(p+12);
#pragma unroll
    for (int i = 0; i < 16; i++) Ls[(cq+i)*80 + e] = f2b(vv[i]*sc);
  }
  __syncthreads();
  {
    const int c8 = tid & 7, r = tid >> 3;
#pragma unroll
    for (int rr0 = 0; rr0 < 2; rr0++){
      int rr = r + rr0*32;
      *(uint4w*)(outp + rr*En + e0 + c8*8) = *(const uint4w*)&Ls[rr*80 + c8*8];
    }
  }
}

// ---------------- kernel 1: QKV GEMM (512 thr / 8 waves, depth-2 vmcnt) ------
// 128x128 tile, BK=64; wave grid 4M x 2N, per-wave 32x64 output. 16 waves/CU.
__global__ void __launch_bounds__(512, 4)
k_qkv(const unsigned short* __restrict__ xb,
      const unsigned short* __restrict__ Wt,
      unsigned short* __restrict__ Qb, unsigned short* __restrict__ Kb,
      unsigned short* __restrict__ Vt)
{
  __shared__ unsigned short As[2][128*64];
  __shared__ unsigned short Bs[2][128*64];
  const int tid = threadIdx.x, lane = tid & 63, w = tid >> 6;  // w in [0,8)
  const int wr = w >> 1, wc = w & 1;                           // 4M x 2N
  const int mb = blockIdx.x, nb = blockIdx.y;
  const int n0 = nb*128;
  const int sel = n0 >> 10;
  const int nj0 = n0 & 1023;
  const int l15 = lane & 15, kc = lane >> 4;
  const int r8 = lane >> 3, c7 = lane & 7;
  const int q4 = (lane >> 4)*4;

  const unsigned short* xbase = xb + (mb*128)*En;
  const unsigned short* wbase = Wt + n0*En;

  f32x4 acc[2][4];
#pragma unroll
  for (int i = 0; i < 2; i++)
#pragma unroll
    for (int j = 0; j < 4; j++) acc[i][j] = (f32x4){0.f,0.f,0.f,0.f};

  auto stage = [&](int buf, int k0){
#pragma unroll
    for (int i = 0; i < 2; i++){
      const int rb = w*16 + i*8;
      const int r = rb + r8;
      const int g = (c7 ^ r8) * 8;
      gl16(xbase + r*En + k0 + g, &As[buf][rb*64]);
      gl16(wbase + r*En + k0 + g, &Bs[buf][rb*64]);
    }
  };
  auto compute = [&](int cur){
    const unsigned short* Ac = &As[cur][0];
    const unsigned short* Bc = &Bs[cur][0];
#pragma unroll
    for (int ks = 0; ks < 2; ks++){
      short8 af[2], bf[4];
#pragma unroll
      for (int mf = 0; mf < 2; mf++){
        int ar = wr*32 + mf*16 + l15;
        af[mf] = *(const short8*)&Ac[ar*64 + (((ks*4 + kc) ^ (ar & 7))*8)];
      }
#pragma unroll
      for (int nf = 0; nf < 4; nf++){
        int br = wc*64 + nf*16 + l15;
        bf[nf] = *(const short8*)&Bc[br*64 + (((ks*4 + kc) ^ (br & 7))*8)];
      }
      __builtin_amdgcn_s_setprio(1);
#pragma unroll
      for (int mf = 0; mf < 2; mf++)
#pragma unroll
        for (int nf = 0; nf < 4; nf++)
          acc[mf][nf] = mfma16(af[mf], bf[nf], acc[mf][nf]);
      __builtin_amdgcn_s_setprio(0);
    }
  };

  stage(0, 0);
  stage(1, 64);
  WAITV(4); SBAR();

  for (int kt = 0; kt < 16; kt++){
    const int cur = kt & 1;
    compute(cur);
    FENCE(); SBAR();
    if (kt < 14){
      stage(cur, (kt + 2)*64);
      WAITV(4); SBAR();
    } else if (kt == 14){
      WAITV(0); SBAR();
    }
  }
  __syncthreads();

  const int bb = mb >> 4;
  const int tt0 = (mb*128) & 2047;

  if (sel == 2){
    // transpose 32(rows) x 64(cols) wave tile through LDS (stride 40 shorts)
    unsigned short* tb = ((w < 4) ? &As[0][0] + w*2560 : &Bs[0][0] + (w-4)*2560);
#pragma unroll
    for (int nf = 0; nf < 4; nf++)
#pragma unroll
      for (int mf = 0; mf < 2; mf++){
        uint2 u;
        u.x = cvtpk(acc[mf][nf][0], acc[mf][nf][1]);
        u.y = cvtpk(acc[mf][nf][2], acc[mf][nf][3]);
        *(uint2*)&tb[(nf*16 + l15)*40 + mf*16 + q4] = u;
      }
    const int hh = (nj0 >> 6) + wc;
    unsigned short* vb = Vt + ((size_t)(bb*Hn + hh)*HSn)*Tn + tt0 + wr*32;
#pragma unroll
    for (int i = 0; i < 4; i++){
      int rr = i*16 + (lane >> 2);
      int c2 = lane & 3;
      *(uint4w*)(vb + (size_t)rr*Tn + c2*8) = *(const uint4w*)&tb[rr*40 + c2*8];
    }
  } else {
    unsigned short* Out = (sel == 1) ? Kb : Qb;
#pragma unroll
    for (int nf = 0; nf < 4; nf++){
      int jj = nj0 + wc*64 + nf*16 + l15;
      int hh = jj >> 6, dd = jj & 63;
#pragma unroll
      for (int mf = 0; mf < 2; mf++){
#pragma unroll
        for (int q = 0; q < 4; q++){
          int tt = tt0 + wr*32 + mf*16 + q4 + q;
          Out[((bb*Hn + hh)*Tn + tt)*HSn + dd] = f2b(acc[mf][nf][q]);
        }
      }
    }
  }
}

// ---------------- kernel 2: column exp-sums + fused V-scale (paired) ---------
// grid (8,128): bh = x*8 + (y&7) XCD-pinned; p0 = y>>3 in [0,16); pair of
// s-blocks {p0 (heavy), 31-p0 (light)} -> every block does ~17 tiles (uniform,
// all 512 blocks co-resident at 2/CU). Inner code identical to R13.
__global__ void __launch_bounds__(256, 3)
k_colsum(const unsigned short* __restrict__ Qb,
         const unsigned short* __restrict__ Kb,
         unsigned short* __restrict__ Vt,
         float* __restrict__ Linv)
{
  __shared__ unsigned short Qs[3][128*64];   // 48KB
  __shared__ float Lred[64];
  const int bh = blockIdx.x*8 + (blockIdx.y & 7);
  const int p0 = blockIdx.y >> 3;            // 0..15; low p0 dispatched first
  const int tid = threadIdx.x, lane = tid & 63, w = tid >> 6;
  const int l5 = lane >> 5, l31 = lane & 31;
  const int r8 = lane >> 3, c7 = lane & 7;

  for (int ph = 0; ph < 2; ph++){
    const int sb = ph ? (31 - p0) : p0;      // heavy first
    const int s0 = sb * 64;

    short8 kf[2][4];
#pragma unroll
    for (int sf = 0; sf < 2; sf++){
      const unsigned short* kr = Kb + (bh*Tn + s0 + sf*32 + l31)*HSn + 8*l5;
#pragma unroll
      for (int ks = 0; ks < 4; ks++) kf[sf][ks] = *(const short8*)(kr + 16*ks);
    }

    float ls[2][16];
#pragma unroll
    for (int sf = 0; sf < 2; sf++)
#pragma unroll
      for (int r = 0; r < 16; r++) ls[sf][r] = 0.f;

    if (tid < 64) Lred[tid] = 0.f;

    const int t0s = (s0 >> 7) << 7;
    const int ntl = (Tn - t0s) >> 7;

    auto stageQ = [&](int buf, int tg0){
#pragma unroll
      for (int i = 0; i < 4; i++){
        int row = (w*4 + i)*8 + r8;
        gl16(Qb + (bh*Tn + tg0 + row)*HSn + ((c7 ^ (row & 7))*8), &Qs[buf][(w*4 + i)*512]);
      }
    };

    // reverse stream: tile index tl = ntl-1-j (suffix-aligned across the bh)
    stageQ(0, t0s + (ntl-1)*128);
    if (ntl > 1) stageQ(1, t0s + (ntl-2)*128);

    for (int j = 0; j < ntl; j++){
      if (j + 1 < ntl){ WAITV(4); } else { WAITV(0); }
      FENCE(); SBAR(); FENCE();
      if (j + 2 < ntl) stageQ((j + 2) % 3, t0s + (ntl-3-j)*128);

      const int cur = j % 3;
      const int t0 = t0s + (ntl-1-j)*128;
      const int tw = t0 + 32*w;
      if (tw + 31 >= s0){
        f32x16 st[2];
#pragma unroll
        for (int sf = 0; sf < 2; sf++)
#pragma unroll
          for (int r = 0; r < 16; r++) st[sf][r] = 0.f;
        const int qrow = w*32 + l31;
        const unsigned short* Qc = &Qs[cur][qrow*64];
        const int sw = qrow & 7;
        __builtin_amdgcn_s_setprio(1);
#pragma unroll
        for (int ks = 0; ks < 4; ks++){
          short8 qb = *(const short8*)&Qc[((l5 + 2*ks) ^ sw)*8];
          st[0] = mfma32(kf[0][ks], qb, st[0]);
          st[1] = mfma32(kf[1][ks], qb, st[1]);
        }
        __builtin_amdgcn_s_setprio(0);
        const int tg = tw + l31;
        if (s0 + 63 <= tw){
#pragma unroll
          for (int sf = 0; sf < 2; sf++)
#pragma unroll
            for (int r = 0; r < 16; r++)
              ls[sf][r] += __builtin_amdgcn_exp2f(st[sf][r]);
        } else {
#pragma unroll
          for (int sf = 0; sf < 2; sf++)
#pragma unroll
            for (int r = 0; r < 16; r++){
              int sg = s0 + 32*sf + (r & 3) + 8*(r >> 2) + 4*l5;
              float e = __builtin_amdgcn_exp2f(st[sf][r]);
              ls[sf][r] += (tg >= sg) ? e : 0.f;
            }
        }
      }
    }

#pragma unroll
    for (int sf = 0; sf < 2; sf++)
#pragma unroll
      for (int r = 0; r < 16; r++){
        float v = ls[sf][r];
        v += __shfl_xor(v, 1);  v += __shfl_xor(v, 2);
        v += __shfl_xor(v, 4);  v += __shfl_xor(v, 8);
        v += __shfl_xor(v, 16);
        ls[sf][r] = v;
      }
    if (l31 == 0){
#pragma unroll
      for (int sf = 0; sf < 2; sf++)
#pragma unroll
        for (int r = 0; r < 16; r++){
          int sl = 32*sf + (r & 3) + 8*(r >> 2) + 4*l5;
          atomicAdd(&Lred[sl], ls[sf][r]);
        }
    }
    __syncthreads();
    if (tid < 64) Linv[bh*Tn + s0 + tid] = 1.0f / Lred[tid];

    // fused V-scale: this block owns columns [s0, s0+64) of Vt for this bh
    {
      const int d = tid >> 2, cq = (tid & 3)*16;
      unsigned short* vp = Vt + ((size_t)(bh*HSn + d))*Tn + s0 + cq;
      short8 v0 = *(const short8*)vp;
      short8 v1 = *(const short8*)(vp + 8);
      float inv[16];
#pragma unroll
      for (int j = 0; j < 16; j++) inv[j] = 1.0f / Lred[cq + j];
      uint4w o0, o1;
      o0[0] = cvtpk(b2f((unsigned short)v0[0])*inv[0],  b2f((unsigned short)v0[1])*inv[1]);
      o0[1] = cvtpk(b2f((unsigned short)v0[2])*inv[2],  b2f((unsigned short)v0[3])*inv[3]);
      o0[2] = cvtpk(b2f((unsigned short)v0[4])*inv[4],  b2f((unsigned short)v0[5])*inv[5]);
      o0[3] = cvtpk(b2f((unsigned short)v0[6])*inv[6],  b2f((unsigned short)v0[7])*inv[7]);
      o1[0] = cvtpk(b2f((unsigned short)v1[0])*inv[8],  b2f((unsigned short)v1[1])*inv[9]);
      o1[1] = cvtpk(b2f((unsigned short)v1[2])*inv[10], b2f((unsigned short)v1[3])*inv[11]);
      o1[2] = cvtpk(b2f((unsigned short)v1[4])*inv[12], b2f((unsigned short)v1[5])*inv[13]);
      o1[3] = cvtpk(b2f((unsigned short)v1[6])*inv[14], b2f((unsigned short)v1[7])*inv[15]);
      *(uint4w*)vp       = o0;
      *(uint4w*)(vp + 8) = o1;
    }
    if (ph == 0) __syncthreads();   // protect Lred reset + Qs reuse in ph1
  }
}

// ---------------- kernel 3: attention output (paired t-blocks) ---------------
// grid (8,64): bh = x*8 + (y&7) XCD-pinned; p0 = y>>3 in [0,8); pair of
// t-blocks {15-p0 (heavy), p0 (light)} -> every block does exactly 34 tiles;
// all 512 blocks co-resident at 2/CU (cap 3). Inner code identical to R13.
__global__ void __launch_bounds__(256, 3)
k_attn(const unsigned short* __restrict__ Qb,
       const unsigned short* __restrict__ Kb,
       const unsigned short* __restrict__ Vlt,
       unsigned short* __restrict__ Att)
{
  __shared__ unsigned short Ks[3][64*64];   // 24KB
  __shared__ unsigned short Vs[3][64*64];   // 24KB
  const int bh = blockIdx.x*8 + (blockIdx.y & 7);
  const int p0 = blockIdx.y >> 3;           // 0..7
  const int tid = threadIdx.x, lane = tid & 63, w = tid >> 6;
  const int l5 = lane >> 5, l31 = lane & 31;
  const int c7 = lane & 7, r8 = lane >> 3;

  auto stageKV = [&](int buf, int sn){
#pragma unroll
    for (int i = 0; i < 2; i++){
      int row = (w*2 + i)*8 + r8;
      gl16(Kb  + (bh*Tn + sn + row)*HSn + ((c7 ^ (row & 7))*8), &Ks[buf][(w*2 + i)*512]);
      gl16(Vlt + ((size_t)(bh*HSn + row))*Tn + sn + ((c7 ^ (row & 7))*8), &Vs[buf][(w*2 + i)*512]);
    }
  };

  for (int ph = 0; ph < 2; ph++){
    const int tb = ph ? p0 : (15 - p0);     // heavy first
    const int t0 = tb * 128;
    const int tbase = t0 + w*32;
    const int nt = 2*tb + 2;

    short8 qf[4];
    {
      const unsigned short* qr = Qb + (bh*Tn + tbase + l31)*HSn + 8*l5;
#pragma unroll
      for (int ks = 0; ks < 4; ks++) qf[ks] = *(const short8*)(qr + 16*ks);
    }

    f32x16 oacc[2];
#pragma unroll
    for (int df = 0; df < 2; df++)
#pragma unroll
      for (int r = 0; r < 16; r++) oacc[df][r] = 0.f;

    stageKV(0, 0);
    if (nt > 1) stageKV(1, 64);

    for (int it = 0; it < nt; it++){
      if (it + 1 < nt){ WAITV(4); } else { WAITV(0); }
      FENCE(); SBAR(); FENCE();
      if (it + 2 < nt) stageKV((it + 2) % 3, (it + 2)*64);

      const int cur = it % 3;
      const int s0 = it * 64;
      if (s0 <= tbase + 31){
        const unsigned short* Kc = &Ks[cur][0];
        f32x16 st[2];
#pragma unroll
        for (int sf = 0; sf < 2; sf++)
#pragma unroll
          for (int r = 0; r < 16; r++) st[sf][r] = 0.f;
        __builtin_amdgcn_s_setprio(1);
#pragma unroll
        for (int ks = 0; ks < 4; ks++){
#pragma unroll
          for (int sf = 0; sf < 2; sf++){
            int row = sf*32 + l31;
            short8 ka = *(const short8*)&Kc[row*64 + (((l5 + 2*ks) ^ (row & 7))*8)];
            st[sf] = mfma32(ka, qf[ks], st[sf]);
          }
        }
        __builtin_amdgcn_s_setprio(0);

        const int tg = tbase + l31;
        const bool interior = (s0 + 63 <= tbase);
#pragma unroll
        for (int sf = 0; sf < 2; sf++){
#pragma unroll
          for (int r = 0; r < 16; r++){
            float e = __builtin_amdgcn_exp2f(st[sf][r]);
            if (!interior){
              int sg = s0 + 32*sf + (r & 3) + 8*(r >> 2) + 4*l5;
              e = (tg >= sg) ? e : 0.f;
            }
            st[sf][r] = e;
          }
        }

        short8 pb[4];
#pragma unroll
        for (int sf = 0; sf < 2; sf++){
#pragma unroll
          for (int q = 0; q < 2; q++){
            unsigned int ax = cvtpk(st[sf][8*q+0], st[sf][8*q+1]);
            unsigned int ay = cvtpk(st[sf][8*q+2], st[sf][8*q+3]);
            unsigned int bx = cvtpk(st[sf][8*q+4], st[sf][8*q+5]);
            unsigned int by = cvtpk(st[sf][8*q+6], st[sf][8*q+7]);
            asm("v_permlane32_swap_b32 %0, %1" : "+v"(ax), "+v"(bx));
            asm("v_permlane32_swap_b32 %0, %1" : "+v"(ay), "+v"(by));
            union { unsigned int u[4]; short8 s; } pk;
            pk.u[0] = ax; pk.u[1] = ay; pk.u[2] = bx; pk.u[3] = by;
            pb[sf*2 + q] = pk.s;
          }
        }

        const unsigned short* Vc = &Vs[cur][0];
        __builtin_amdgcn_s_setprio(1);
#pragma unroll
        for (int ks = 0; ks < 4; ks++){
#pragma unroll
          for (int df = 0; df < 2; df++){
            int row = df*32 + l31;
            short8 va = *(const short8*)&Vc[row*64 + (((l5 + 2*ks) ^ (row & 7))*8)];
            oacc[df] = mfma32(va, pb[ks], oacc[df]);
          }
        }
        __builtin_amdgcn_s_setprio(0);
      }
    }

    {
      const int tg = tbase + l31;
      unsigned short* ob = Att + (bh*Tn + tg)*HSn;
#pragma unroll
      for (int df = 0; df < 2; df++)
#pragma unroll
        for (int r2 = 0; r2 < 4; r2++){
          uint2 u;
          u.x = cvtpk(oacc[df][r2*4+0], oacc[df][r2*4+1]);
          u.y = cvtpk(oacc[df][r2*4+2], oacc[df][r2*4+3]);
          *(uint2*)&ob[32*df + 8*r2 + 4*l5] = u;
        }
    }
    if (ph == 0) __syncthreads();   // all waves done with ph0 buffers before ph1 staging
  }
}

// ---------------- kernel 4: output projection (512 thr / 8 waves) ------------
__global__ void __launch_bounds__(512, 4)
k_oproj(const unsigned short* __restrict__ Att,
        const unsigned short* __restrict__ Wot,
        const float* __restrict__ bo, float* __restrict__ out)
{
  __shared__ unsigned short As[2][128*64];
  __shared__ unsigned short Bs[2][128*64];
  const int tid = threadIdx.x, lane = tid & 63, w = tid >> 6;  // w in [0,8)
  const int wr = w >> 1, wc = w & 1;
  const int mb = blockIdx.x, nb = blockIdx.y;
  const int n0 = nb*128;
  const int l15 = lane & 15, kc = lane >> 4;
  const int r8 = lane >> 3, c7 = lane & 7;
  const int q4 = (lane >> 4)*4;
  const int bb = mb >> 4;
  const int t0 = (mb*128) & 2047;

  f32x4 acc[2][4];
#pragma unroll
  for (int i = 0; i < 2; i++)
#pragma unroll
    for (int j = 0; j < 4; j++) acc[i][j] = (f32x4){0.f,0.f,0.f,0.f};

  const unsigned short* wbase = Wot + n0*En;

  auto stage = [&](int buf, int k0){
    const int hh = k0 >> 6;
    const unsigned short* abase = Att + ((bb*Hn + hh)*Tn + t0)*HSn;
#pragma unroll
    for (int i = 0; i < 2; i++){
      const int rb = w*16 + i*8;
      const int r = rb + r8;
      const int g = (c7 ^ r8) * 8;
      gl16(abase + r*HSn + g, &As[buf][rb*64]);
      gl16(wbase + r*En + k0 + g, &Bs[buf][rb*64]);
    }
  };
  auto compute = [&](int cur){
    const unsigned short* Ac = &As[cur][0];
    const unsigned short* Bc = &Bs[cur][0];
#pragma unroll
    for (int ks = 0; ks < 2; ks++){
      short8 af[2], bf[4];
#pragma unroll
      for (int mf = 0; mf < 2; mf++){
        int ar = wr*32 + mf*16 + l15;
        af[mf] = *(const short8*)&Ac[ar*64 + (((ks*4 + kc) ^ (ar & 7))*8)];
      }
#pragma unroll
      for (int nf = 0; nf < 4; nf++){
        int br = wc*64 + nf*16 + l15;
        bf[nf] = *(const short8*)&Bc[br*64 + (((ks*4 + kc) ^ (br & 7))*8)];
      }
      __builtin_amdgcn_s_setprio(1);
#pragma unroll
      for (int mf = 0; mf < 2; mf++)
#pragma unroll
        for (int nf = 0; nf < 4; nf++)
          acc[mf][nf] = mfma16(af[mf], bf[nf], acc[mf][nf]);
      __builtin_amdgcn_s_setprio(0);
    }
  };

  stage(0, 0);
  stage(1, 64);
  WAITV(4); SBAR();

  for (int kt = 0; kt < 16; kt++){
    const int cur = kt & 1;
    compute(cur);
    FENCE(); SBAR();
    if (kt < 14){
      stage(cur, (kt + 2)*64);
      WAITV(4); SBAR();
    } else if (kt == 14){
      WAITV(0); SBAR();
    }
  }

#pragma unroll
  for (int nf = 0; nf < 4; nf++){
    int j = n0 + wc*64 + nf*16 + l15;
    float bias = bo[j];
#pragma unroll
    for (int mf = 0; mf < 2; mf++){
#pragma unroll
      for (int q = 0; q < 4; q++){
        int rr = mb*128 + wr*32 + mf*16 + q4 + q;
        out[rr*En + j] = acc[mf][nf][q] + bias;
      }
    }
  }
}

extern "C" void kernel_launch(void* const* d_in, const int* in_sizes, int n_in,
                              void* d_out, int out_size, void* d_ws, size_t ws_size,
                              hipStream_t stream)
{
  (void)in_sizes; (void)n_in; (void)out_size; (void)ws_size;
  const float* x  = (const float*)d_in[0];
  const float* Wq = (const float*)d_in[1];
  const float* Wk = (const float*)d_in[2];
  const float* Wv = (const float*)d_in[3];
  const float* Wo = (const float*)d_in[4];
  const float* bo = (const float*)d_in[5];
  float* out = (float*)d_out;

  // ws layout (MB): Qb[0,16) Kb[16,32) Vt[32,48) xb/Att[48,64) Wt[64,70) Wot[70,72) Linv[72,72.5)
  uint8_t* w = (uint8_t*)d_ws;
  unsigned short* Qb  = (unsigned short*)(w);
  unsigned short* Kb  = (unsigned short*)(w + (16u << 20));
  unsigned short* Vt  = (unsigned short*)(w + (32u << 20));
  unsigned short* xb  = (unsigned short*)(w + (48u << 20));
  unsigned short* Att = (unsigned short*)(w + (48u << 20));
  unsigned short* Wt  = (unsigned short*)(w + (64u << 20));
  unsigned short* Wot = (unsigned short*)(w + (70u << 20));
  float* Linv         = (float*)(w + (72u << 20));

  hipLaunchKernelGGL(k_cvt_x,  dim3(4096),    dim3(256), 0, stream, x, xb);
  hipLaunchKernelGGL(k_wT,     dim3(16, 64),  dim3(256), 0, stream, Wq, Wk, Wv, Wo, Wt, Wot);
  hipLaunchKernelGGL(k_qkv,    dim3(64, 24),  dim3(512), 0, stream, xb, Wt, Qb, Kb, Vt);
  hipLaunchKernelGGL(k_colsum, dim3(8, 128),  dim3(256), 0, stream, Qb, Kb, Vt, Linv);
  hipLaunchKernelGGL(k_attn,   dim3(8, 64),   dim3(256), 0, stream, Qb, Kb, Vt, Att);
  hipLaunchKernelGGL(k_oproj,  dim3(64, 8),   dim3(512), 0, stream, Att, Wot, bo, out);
}

// Round 15
// 195.305 us; speedup vs baseline: 1.0722x; 1.0722x over previous
//
#include <hip/hip_runtime.h>
#include <stdint.h>

// Problem constants
#define Bn 4
#define Tn 2048
#define En 1024
#define Hn 16
#define HSn 64
#define BHn (Bn*Hn)   // 64
#define NRn (Bn*Tn)   // 8192

// exp(x/32) = exp2(x * 0.03125 * log2(e)); folded into Wq at k_wT time.
#define CEXP 0.0450840831f

typedef __attribute__((ext_vector_type(8))) short short8;
typedef __attribute__((ext_vector_type(4))) float f32x4;
typedef __attribute__((ext_vector_type(16))) float f32x16;
typedef __attribute__((ext_vector_type(4))) unsigned int uint4w;

__device__ __forceinline__ unsigned short f2b(float f){
  union { float f; unsigned int u; } c; c.f = f;
  unsigned int u = c.u + 0x7FFFu + ((c.u >> 16) & 1u);
  return (unsigned short)(u >> 16);
}
__device__ __forceinline__ float b2f(unsigned short s){
  union { unsigned int u; float f; } c; c.u = ((unsigned int)s) << 16;
  return c.f;
}
__device__ __forceinline__ unsigned int cvtpk(float lo, float hi){
  unsigned int r;
  asm("v_cvt_pk_bf16_f32 %0, %1, %2" : "=v"(r) : "v"(lo), "v"(hi));
  return r;
}
__device__ __forceinline__ f32x4 mfma16(short8 a, short8 b, f32x4 c){
  return __builtin_amdgcn_mfma_f32_16x16x32_bf16(a, b, c, 0, 0, 0);
}
__device__ __forceinline__ f32x16 mfma32(short8 a, short8 b, f32x16 c){
  return __builtin_amdgcn_mfma_f32_32x32x16_bf16(a, b, c, 0, 0, 0);
}
__device__ __forceinline__ void gl16(const void* g, void* s){
  __builtin_amdgcn_global_load_lds((const __attribute__((address_space(1))) unsigned int*)g,
                                   (__attribute__((address_space(3))) unsigned int*)s, 16, 0, 0);
}
#define FENCE()    asm volatile("" ::: "memory")
#define WAITV(N)   asm volatile("s_waitcnt vmcnt(" #N ")" ::: "memory")
#define SBAR()     __builtin_amdgcn_s_barrier()

// ---------------- kernel 0: x fp32 -> bf16 ----------------
__global__ void k_cvt_x(const float* __restrict__ x, unsigned short* __restrict__ xb){
  int i = (blockIdx.x * blockDim.x + threadIdx.x) * 8;
  float4 a = *(const float4*)(x + i);
  float4 b = *(const float4*)(x + i + 4);
  alignas(16) unsigned short o[8] = {f2b(a.x),f2b(a.y),f2b(a.z),f2b(a.w),
                                     f2b(b.x),f2b(b.y),f2b(b.z),f2b(b.w)};
  *(uint4w*)(xb + i) = *(const uint4w*)o;
}

// ---------------- kernel 0b: weight convert+transpose (Wq pre-scaled) --------
__global__ void k_wT(const float* __restrict__ Wq, const float* __restrict__ Wk,
                     const float* __restrict__ Wv, const float* __restrict__ Wo,
                     unsigned short* __restrict__ Wt, unsigned short* __restrict__ Wot)
{
  __shared__ unsigned short Ls[64*80];
  const int tid = threadIdx.x;
  const int ey = blockIdx.x, jt = blockIdx.y;
  const int e0 = ey*64;
  const float* src; int R, c0; unsigned short* outp; float sc = 1.0f;
  if (jt < 48){
    int sel = jt >> 4, h = jt & 15;
    const float* W = (sel==0)?Wq:((sel==1)?Wk:Wv);
    if (sel == 0) sc = CEXP;          // fold exp2 conversion+1/32 into Q
    src = W + h*(En*HSn); R = HSn; c0 = 0;
    outp = Wt + jt*64*En;
  } else {
    src = Wo; R = En; c0 = (jt-48)*64;
    outp = Wot + (jt-48)*64*En;
  }
  {
    const int e = tid >> 2, cq = (tid & 3)*16;
    const float* p = src + (e0 + e)*R + c0 + cq;
    float vv[16];
    *(float4*)&vv[0]  = *(const float4*)(p);
    *(float4*)&vv[4]  = *(const float4*)(p+4);
    *(float4*)&vv[8]  = *(const float4*)(p+8);
    *(float4*)&vv[12] = *(const float4*)(p+12);
#pragma unroll
    for (int i = 0; i < 16; i++) Ls[(cq+i)*80 + e] = f2b(vv[i]*sc);
  }
  __syncthreads();
  {
    const int c8 = tid & 7, r = tid >> 3;
#pragma unroll
    for (int rr0 = 0; rr0 < 2; rr0++){
      int rr = r + rr0*32;
      *(uint4w*)(outp + rr*En + e0 + c8*8) = *(const uint4w*)&Ls[rr*80 + c8*8];
    }
  }
}

// ---------------- kernel 1: QKV GEMM (512 thr / 8 waves, depth-2 vmcnt) ------
// 128x128 tile, BK=64; wave grid 4M x 2N, per-wave 32x64 output. 16 waves/CU.
__global__ void __launch_bounds__(512, 4)
k_qkv(const unsigned short* __restrict__ xb,
      const unsigned short* __restrict__ Wt,
      unsigned short* __restrict__ Qb, unsigned short* __restrict__ Kb,
      unsigned short* __restrict__ Vt)
{
  __shared__ unsigned short As[2][128*64];
  __shared__ unsigned short Bs[2][128*64];
  const int tid = threadIdx.x, lane = tid & 63, w = tid >> 6;  // w in [0,8)
  const int wr = w >> 1, wc = w & 1;                           // 4M x 2N
  const int mb = blockIdx.x, nb = blockIdx.y;
  const int n0 = nb*128;
  const int sel = n0 >> 10;
  const int nj0 = n0 & 1023;
  const int l15 = lane & 15, kc = lane >> 4;
  const int r8 = lane >> 3, c7 = lane & 7;
  const int q4 = (lane >> 4)*4;

  const unsigned short* xbase = xb + (mb*128)*En;
  const unsigned short* wbase = Wt + n0*En;

  f32x4 acc[2][4];
#pragma unroll
  for (int i = 0; i < 2; i++)
#pragma unroll
    for (int j = 0; j < 4; j++) acc[i][j] = (f32x4){0.f,0.f,0.f,0.f};

  auto stage = [&](int buf, int k0){
#pragma unroll
    for (int i = 0; i < 2; i++){
      const int rb = w*16 + i*8;
      const int r = rb + r8;
      const int g = (c7 ^ r8) * 8;
      gl16(xbase + r*En + k0 + g, &As[buf][rb*64]);
      gl16(wbase + r*En + k0 + g, &Bs[buf][rb*64]);
    }
  };
  auto compute = [&](int cur){
    const unsigned short* Ac = &As[cur][0];
    const unsigned short* Bc = &Bs[cur][0];
#pragma unroll
    for (int ks = 0; ks < 2; ks++){
      short8 af[2], bf[4];
#pragma unroll
      for (int mf = 0; mf < 2; mf++){
        int ar = wr*32 + mf*16 + l15;
        af[mf] = *(const short8*)&Ac[ar*64 + (((ks*4 + kc) ^ (ar & 7))*8)];
      }
#pragma unroll
      for (int nf = 0; nf < 4; nf++){
        int br = wc*64 + nf*16 + l15;
        bf[nf] = *(const short8*)&Bc[br*64 + (((ks*4 + kc) ^ (br & 7))*8)];
      }
      __builtin_amdgcn_s_setprio(1);
#pragma unroll
      for (int mf = 0; mf < 2; mf++)
#pragma unroll
        for (int nf = 0; nf < 4; nf++)
          acc[mf][nf] = mfma16(af[mf], bf[nf], acc[mf][nf]);
      __builtin_amdgcn_s_setprio(0);
    }
  };

  stage(0, 0);
  stage(1, 64);
  WAITV(4); SBAR();

  for (int kt = 0; kt < 16; kt++){
    const int cur = kt & 1;
    compute(cur);
    FENCE(); SBAR();
    if (kt < 14){
      stage(cur, (kt + 2)*64);
      WAITV(4); SBAR();
    } else if (kt == 14){
      WAITV(0); SBAR();
    }
  }
  __syncthreads();

  const int bb = mb >> 4;
  const int tt0 = (mb*128) & 2047;

  if (sel == 2){
    // transpose 32(rows) x 64(cols) wave tile through LDS (stride 40 shorts)
    unsigned short* tb = ((w < 4) ? &As[0][0] + w*2560 : &Bs[0][0] + (w-4)*2560);
#pragma unroll
    for (int nf = 0; nf < 4; nf++)
#pragma unroll
      for (int mf = 0; mf < 2; mf++){
        uint2 u;
        u.x = cvtpk(acc[mf][nf][0], acc[mf][nf][1]);
        u.y = cvtpk(acc[mf][nf][2], acc[mf][nf][3]);
        *(uint2*)&tb[(nf*16 + l15)*40 + mf*16 + q4] = u;
      }
    const int hh = (nj0 >> 6) + wc;
    unsigned short* vb = Vt + ((size_t)(bb*Hn + hh)*HSn)*Tn + tt0 + wr*32;
#pragma unroll
    for (int i = 0; i < 4; i++){
      int rr = i*16 + (lane >> 2);
      int c2 = lane & 3;
      *(uint4w*)(vb + (size_t)rr*Tn + c2*8) = *(const uint4w*)&tb[rr*40 + c2*8];
    }
  } else {
    unsigned short* Out = (sel == 1) ? Kb : Qb;
#pragma unroll
    for (int nf = 0; nf < 4; nf++){
      int jj = nj0 + wc*64 + nf*16 + l15;
      int hh = jj >> 6, dd = jj & 63;
#pragma unroll
      for (int mf = 0; mf < 2; mf++){
#pragma unroll
        for (int q = 0; q < 4; q++){
          int tt = tt0 + wr*32 + mf*16 + q4 + q;
          Out[((bb*Hn + hh)*Tn + tt)*HSn + dd] = f2b(acc[mf][nf][q]);
        }
      }
    }
  }
}

// ---------------- kernel 2: column exp-sums + fused V-scale -------------------
__global__ void __launch_bounds__(256, 3)
k_colsum(const unsigned short* __restrict__ Qb,
         const unsigned short* __restrict__ Kb,
         unsigned short* __restrict__ Vt,
         float* __restrict__ Linv)
{
  __shared__ unsigned short Qs[3][128*64];   // 48KB
  __shared__ float Lred[64];
  const int bh = blockIdx.x*8 + (blockIdx.y & 7);
  const int sb = blockIdx.y >> 3;            // heavy (low sb) dispatched first
  const int s0 = sb * 64;
  const int tid = threadIdx.x, lane = tid & 63, w = tid >> 6;
  const int l5 = lane >> 5, l31 = lane & 31;
  const int r8 = lane >> 3, c7 = lane & 7;

  short8 kf[2][4];
#pragma unroll
  for (int sf = 0; sf < 2; sf++){
    const unsigned short* kr = Kb + (bh*Tn + s0 + sf*32 + l31)*HSn + 8*l5;
#pragma unroll
    for (int ks = 0; ks < 4; ks++) kf[sf][ks] = *(const short8*)(kr + 16*ks);
  }

  float ls[2][16];
#pragma unroll
  for (int sf = 0; sf < 2; sf++)
#pragma unroll
    for (int r = 0; r < 16; r++) ls[sf][r] = 0.f;

  if (tid < 64) Lred[tid] = 0.f;

  const int t0s = (s0 >> 7) << 7;
  const int ntl = (Tn - t0s) >> 7;

  auto stageQ = [&](int buf, int tg0){
#pragma unroll
    for (int i = 0; i < 4; i++){
      int row = (w*4 + i)*8 + r8;
      gl16(Qb + (bh*Tn + tg0 + row)*HSn + ((c7 ^ (row & 7))*8), &Qs[buf][(w*4 + i)*512]);
    }
  };

  // reverse stream: tile index tl = ntl-1-j (suffix-aligned across the bh)
  stageQ(0, t0s + (ntl-1)*128);
  if (ntl > 1) stageQ(1, t0s + (ntl-2)*128);

  for (int j = 0; j < ntl; j++){
    if (j + 1 < ntl){ WAITV(4); } else { WAITV(0); }
    FENCE(); SBAR(); FENCE();
    if (j + 2 < ntl) stageQ((j + 2) % 3, t0s + (ntl-3-j)*128);

    const int cur = j % 3;
    const int t0 = t0s + (ntl-1-j)*128;
    const int tw = t0 + 32*w;
    if (tw + 31 >= s0){
      f32x16 st[2];
#pragma unroll
      for (int sf = 0; sf < 2; sf++)
#pragma unroll
        for (int r = 0; r < 16; r++) st[sf][r] = 0.f;
      const int qrow = w*32 + l31;
      const unsigned short* Qc = &Qs[cur][qrow*64];
      const int sw = qrow & 7;
      __builtin_amdgcn_s_setprio(1);
#pragma unroll
      for (int ks = 0; ks < 4; ks++){
        short8 qb = *(const short8*)&Qc[((l5 + 2*ks) ^ sw)*8];
        st[0] = mfma32(kf[0][ks], qb, st[0]);
        st[1] = mfma32(kf[1][ks], qb, st[1]);
      }
      __builtin_amdgcn_s_setprio(0);
      const int tg = tw + l31;
      if (s0 + 63 <= tw){
#pragma unroll
        for (int sf = 0; sf < 2; sf++)
#pragma unroll
          for (int r = 0; r < 16; r++)
            ls[sf][r] += __builtin_amdgcn_exp2f(st[sf][r]);
      } else {
#pragma unroll
        for (int sf = 0; sf < 2; sf++)
#pragma unroll
          for (int r = 0; r < 16; r++){
            int sg = s0 + 32*sf + (r & 3) + 8*(r >> 2) + 4*l5;
            float e = __builtin_amdgcn_exp2f(st[sf][r]);
            ls[sf][r] += (tg >= sg) ? e : 0.f;
          }
      }
    }
  }

#pragma unroll
  for (int sf = 0; sf < 2; sf++)
#pragma unroll
    for (int r = 0; r < 16; r++){
      float v = ls[sf][r];
      v += __shfl_xor(v, 1);  v += __shfl_xor(v, 2);
      v += __shfl_xor(v, 4);  v += __shfl_xor(v, 8);
      v += __shfl_xor(v, 16);
      ls[sf][r] = v;
    }
  if (l31 == 0){
#pragma unroll
    for (int sf = 0; sf < 2; sf++)
#pragma unroll
      for (int r = 0; r < 16; r++){
        int sl = 32*sf + (r & 3) + 8*(r >> 2) + 4*l5;
        atomicAdd(&Lred[sl], ls[sf][r]);
      }
  }
  __syncthreads();
  if (tid < 64) Linv[bh*Tn + s0 + tid] = 1.0f / Lred[tid];

  // fused V-scale: this block owns columns [s0, s0+64) of Vt for this bh
  {
    const int d = tid >> 2, cq = (tid & 3)*16;
    unsigned short* vp = Vt + ((size_t)(bh*HSn + d))*Tn + s0 + cq;
    short8 v0 = *(const short8*)vp;
    short8 v1 = *(const short8*)(vp + 8);
    float inv[16];
#pragma unroll
    for (int j = 0; j < 16; j++) inv[j] = 1.0f / Lred[cq + j];
    uint4w o0, o1;
    o0[0] = cvtpk(b2f((unsigned short)v0[0])*inv[0],  b2f((unsigned short)v0[1])*inv[1]);
    o0[1] = cvtpk(b2f((unsigned short)v0[2])*inv[2],  b2f((unsigned short)v0[3])*inv[3]);
    o0[2] = cvtpk(b2f((unsigned short)v0[4])*inv[4],  b2f((unsigned short)v0[5])*inv[5]);
    o0[3] = cvtpk(b2f((unsigned short)v0[6])*inv[6],  b2f((unsigned short)v0[7])*inv[7]);
    o1[0] = cvtpk(b2f((unsigned short)v1[0])*inv[8],  b2f((unsigned short)v1[1])*inv[9]);
    o1[1] = cvtpk(b2f((unsigned short)v1[2])*inv[10], b2f((unsigned short)v1[3])*inv[11]);
    o1[2] = cvtpk(b2f((unsigned short)v1[4])*inv[12], b2f((unsigned short)v1[5])*inv[13]);
    o1[3] = cvtpk(b2f((unsigned short)v1[6])*inv[14], b2f((unsigned short)v1[7])*inv[15]);
    *(uint4w*)vp       = o0;
    *(uint4w*)(vp + 8) = o1;
  }
}

// ---------------- kernel 3: attention output (R10 structure, XCD-grouped) ----
// grid (8, 128): bh = x*8 + (y&7) -> one XCD per bh; tb = 15-(y>>3) heavy-first;
// 3-buffer / 1-barrier rotation, counted vmcnt; permlane in-register P exchange.
__global__ void __launch_bounds__(256, 3)
k_attn(const unsigned short* __restrict__ Qb,
       const unsigned short* __restrict__ Kb,
       const unsigned short* __restrict__ Vlt,
       unsigned short* __restrict__ Att)
{
  __shared__ unsigned short Ks[3][64*64];   // 24KB
  __shared__ unsigned short Vs[3][64*64];   // 24KB
  const int bh = blockIdx.x*8 + (blockIdx.y & 7);
  const int tb = 15 - (blockIdx.y >> 3);    // heavy blocks dispatch first
  const int t0 = tb * 128;
  const int tid = threadIdx.x, lane = tid & 63, w = tid >> 6;
  const int l5 = lane >> 5, l31 = lane & 31;
  const int c7 = lane & 7, r8 = lane >> 3;
  const int tbase = t0 + w*32;
  const int nt = 2*tb + 2;

  short8 qf[4];
  {
    const unsigned short* qr = Qb + (bh*Tn + tbase + l31)*HSn + 8*l5;
#pragma unroll
    for (int ks = 0; ks < 4; ks++) qf[ks] = *(const short8*)(qr + 16*ks);
  }

  f32x16 oacc[2];
#pragma unroll
  for (int df = 0; df < 2; df++)
#pragma unroll
    for (int r = 0; r < 16; r++) oacc[df][r] = 0.f;

  auto stageKV = [&](int buf, int sn){
#pragma unroll
    for (int i = 0; i < 2; i++){
      int row = (w*2 + i)*8 + r8;
      gl16(Kb  + (bh*Tn + sn + row)*HSn + ((c7 ^ (row & 7))*8), &Ks[buf][(w*2 + i)*512]);
      gl16(Vlt + ((size_t)(bh*HSn + row))*Tn + sn + ((c7 ^ (row & 7))*8), &Vs[buf][(w*2 + i)*512]);
    }
  };

  stageKV(0, 0);
  if (nt > 1) stageKV(1, 64);

  for (int it = 0; it < nt; it++){
    if (it + 1 < nt){ WAITV(4); } else { WAITV(0); }
    FENCE(); SBAR(); FENCE();
    if (it + 2 < nt) stageKV((it + 2) % 3, (it + 2)*64);

    const int cur = it % 3;
    const int s0 = it * 64;
    if (s0 <= tbase + 31){
      const unsigned short* Kc = &Ks[cur][0];
      f32x16 st[2];
#pragma unroll
      for (int sf = 0; sf < 2; sf++)
#pragma unroll
        for (int r = 0; r < 16; r++) st[sf][r] = 0.f;
      __builtin_amdgcn_s_setprio(1);
#pragma unroll
      for (int ks = 0; ks < 4; ks++){
#pragma unroll
        for (int sf = 0; sf < 2; sf++){
          int row = sf*32 + l31;
          short8 ka = *(const short8*)&Kc[row*64 + (((l5 + 2*ks) ^ (row & 7))*8)];
          st[sf] = mfma32(ka, qf[ks], st[sf]);
        }
      }
      __builtin_amdgcn_s_setprio(0);

      const int tg = tbase + l31;
      const bool interior = (s0 + 63 <= tbase);
#pragma unroll
      for (int sf = 0; sf < 2; sf++){
#pragma unroll
        for (int r = 0; r < 16; r++){
          float e = __builtin_amdgcn_exp2f(st[sf][r]);
          if (!interior){
            int sg = s0 + 32*sf + (r & 3) + 8*(r >> 2) + 4*l5;
            e = (tg >= sg) ? e : 0.f;
          }
          st[sf][r] = e;
        }
      }

      short8 pb[4];
#pragma unroll
      for (int sf = 0; sf < 2; sf++){
#pragma unroll
        for (int q = 0; q < 2; q++){
          unsigned int ax = cvtpk(st[sf][8*q+0], st[sf][8*q+1]);
          unsigned int ay = cvtpk(st[sf][8*q+2], st[sf][8*q+3]);
          unsigned int bx = cvtpk(st[sf][8*q+4], st[sf][8*q+5]);
          unsigned int by = cvtpk(st[sf][8*q+6], st[sf][8*q+7]);
          asm("v_permlane32_swap_b32 %0, %1" : "+v"(ax), "+v"(bx));
          asm("v_permlane32_swap_b32 %0, %1" : "+v"(ay), "+v"(by));
          union { unsigned int u[4]; short8 s; } pk;
          pk.u[0] = ax; pk.u[1] = ay; pk.u[2] = bx; pk.u[3] = by;
          pb[sf*2 + q] = pk.s;
        }
      }

      const unsigned short* Vc = &Vs[cur][0];
      __builtin_amdgcn_s_setprio(1);
#pragma unroll
      for (int ks = 0; ks < 4; ks++){
#pragma unroll
        for (int df = 0; df < 2; df++){
          int row = df*32 + l31;
          short8 va = *(const short8*)&Vc[row*64 + (((l5 + 2*ks) ^ (row & 7))*8)];
          oacc[df] = mfma32(va, pb[ks], oacc[df]);
        }
      }
      __builtin_amdgcn_s_setprio(0);
    }
  }

  {
    const int tg = tbase + l31;
    unsigned short* ob = Att + (bh*Tn + tg)*HSn;
#pragma unroll
    for (int df = 0; df < 2; df++)
#pragma unroll
      for (int r2 = 0; r2 < 4; r2++){
        uint2 u;
        u.x = cvtpk(oacc[df][r2*4+0], oacc[df][r2*4+1]);
        u.y = cvtpk(oacc[df][r2*4+2], oacc[df][r2*4+3]);
        *(uint2*)&ob[32*df + 8*r2 + 4*l5] = u;
      }
  }
}

// ---------------- kernel 4: output projection (512 thr / 8 waves) ------------
__global__ void __launch_bounds__(512, 4)
k_oproj(const unsigned short* __restrict__ Att,
        const unsigned short* __restrict__ Wot,
        const float* __restrict__ bo, float* __restrict__ out)
{
  __shared__ unsigned short As[2][128*64];
  __shared__ unsigned short Bs[2][128*64];
  const int tid = threadIdx.x, lane = tid & 63, w = tid >> 6;  // w in [0,8)
  const int wr = w >> 1, wc = w & 1;
  const int mb = blockIdx.x, nb = blockIdx.y;
  const int n0 = nb*128;
  const int l15 = lane & 15, kc = lane >> 4;
  const int r8 = lane >> 3, c7 = lane & 7;
  const int q4 = (lane >> 4)*4;
  const int bb = mb >> 4;
  const int t0 = (mb*128) & 2047;

  f32x4 acc[2][4];
#pragma unroll
  for (int i = 0; i < 2; i++)
#pragma unroll
    for (int j = 0; j < 4; j++) acc[i][j] = (f32x4){0.f,0.f,0.f,0.f};

  const unsigned short* wbase = Wot + n0*En;

  auto stage = [&](int buf, int k0){
    const int hh = k0 >> 6;
    const unsigned short* abase = Att + ((bb*Hn + hh)*Tn + t0)*HSn;
#pragma unroll
    for (int i = 0; i < 2; i++){
      const int rb = w*16 + i*8;
      const int r = rb + r8;
      const int g = (c7 ^ r8) * 8;
      gl16(abase + r*HSn + g, &As[buf][rb*64]);
      gl16(wbase + r*En + k0 + g, &Bs[buf][rb*64]);
    }
  };
  auto compute = [&](int cur){
    const unsigned short* Ac = &As[cur][0];
    const unsigned short* Bc = &Bs[cur][0];
#pragma unroll
    for (int ks = 0; ks < 2; ks++){
      short8 af[2], bf[4];
#pragma unroll
      for (int mf = 0; mf < 2; mf++){
        int ar = wr*32 + mf*16 + l15;
        af[mf] = *(const short8*)&Ac[ar*64 + (((ks*4 + kc) ^ (ar & 7))*8)];
      }
#pragma unroll
      for (int nf = 0; nf < 4; nf++){
        int br = wc*64 + nf*16 + l15;
        bf[nf] = *(const short8*)&Bc[br*64 + (((ks*4 + kc) ^ (br & 7))*8)];
      }
      __builtin_amdgcn_s_setprio(1);
#pragma unroll
      for (int mf = 0; mf < 2; mf++)
#pragma unroll
        for (int nf = 0; nf < 4; nf++)
          acc[mf][nf] = mfma16(af[mf], bf[nf], acc[mf][nf]);
      __builtin_amdgcn_s_setprio(0);
    }
  };

  stage(0, 0);
  stage(1, 64);
  WAITV(4); SBAR();

  for (int kt = 0; kt < 16; kt++){
    const int cur = kt & 1;
    compute(cur);
    FENCE(); SBAR();
    if (kt < 14){
      stage(cur, (kt + 2)*64);
      WAITV(4); SBAR();
    } else if (kt == 14){
      WAITV(0); SBAR();
    }
  }

#pragma unroll
  for (int nf = 0; nf < 4; nf++){
    int j = n0 + wc*64 + nf*16 + l15;
    float bias = bo[j];
#pragma unroll
    for (int mf = 0; mf < 2; mf++){
#pragma unroll
      for (int q = 0; q < 4; q++){
        int rr = mb*128 + wr*32 + mf*16 + q4 + q;
        out[rr*En + j] = acc[mf][nf][q] + bias;
      }
    }
  }
}

extern "C" void kernel_launch(void* const* d_in, const int* in_sizes, int n_in,
                              void* d_out, int out_size, void* d_ws, size_t ws_size,
                              hipStream_t stream)
{
  (void)in_sizes; (void)n_in; (void)out_size; (void)ws_size;
  const float* x  = (const float*)d_in[0];
  const float* Wq = (const float*)d_in[1];
  const float* Wk = (const float*)d_in[2];
  const float* Wv = (const float*)d_in[3];
  const float* Wo = (const float*)d_in[4];
  const float* bo = (const float*)d_in[5];
  float* out = (float*)d_out;

  // ws layout (MB): Qb[0,16) Kb[16,32) Vt[32,48) xb/Att[48,64) Wt[64,70) Wot[70,72) Linv[72,72.5)
  uint8_t* w = (uint8_t*)d_ws;
  unsigned short* Qb  = (unsigned short*)(w);
  unsigned short* Kb  = (unsigned short*)(w + (16u << 20));
  unsigned short* Vt  = (unsigned short*)(w + (32u << 20));
  unsigned short* xb  = (unsigned short*)(w + (48u << 20));
  unsigned short* Att = (unsigned short*)(w + (48u << 20));
  unsigned short* Wt  = (unsigned short*)(w + (64u << 20));
  unsigned short* Wot = (unsigned short*)(w + (70u << 20));
  float* Linv         = (float*)(w + (72u << 20));

  hipLaunchKernelGGL(k_cvt_x,  dim3(4096),    dim3(256), 0, stream, x, xb);
  hipLaunchKernelGGL(k_wT,     dim3(16, 64),  dim3(256), 0, stream, Wq, Wk, Wv, Wo, Wt, Wot);
  hipLaunchKernelGGL(k_qkv,    dim3(64, 24),  dim3(512), 0, stream, xb, Wt, Qb, Kb, Vt);
  hipLaunchKernelGGL(k_colsum, dim3(8, 256),  dim3(256), 0, stream, Qb, Kb, Vt, Linv);
  hipLaunchKernelGGL(k_attn,   dim3(8, 128),  dim3(256), 0, stream, Qb, Kb, Vt, Att);
  hipLaunchKernelGGL(k_oproj,  dim3(64, 8),   dim3(512), 0, stream, Att, Wot, bo, out);
}